// Round 19
// baseline (85.501 us; speedup 1.0000x reference)
//
#include <hip/hip_runtime.h>
#include <hip/hip_bf16.h>
#include <cstdint>
#include <cstddef>

// Problem constants (B=8, T=64, F=16, E=256, H=8)
constexpr int E = 256;
constexpr int H = 8;
constexpr int D = 32;        // head dim
constexpr int N = 1024;      // T*F positions per (b,h)
constexpr int R = 8192;      // B*N rows
constexpr int BH = 64;       // B*H
constexpr float SCALE = 0.17677669529663687f;   // 1/sqrt(32)
constexpr float LOG2E = 1.4426950408889634f;
constexpr float QSCALE = SCALE * LOG2E;          // folded into bf16 Q

// ---- MFMA fragment layout -------------------------------------------------
// idx = ((tile*CCH + (k>>3))*16 + (row&15))*8 + (k&7)
//   Q/K  : tile = bh*64 + (n>>4), CCH = 4  (D=32)
//   V    : tile = m>>4,           CCH = 32 (E=256)
// W is no longer pre-transposed to global: proj/out stage their W-half into
// LDS in this same fragment layout at block start (convw kernel eliminated).

typedef __attribute__((ext_vector_type(8))) short short8;
typedef __attribute__((ext_vector_type(4))) short short4v;
typedef __attribute__((ext_vector_type(4))) float f32x4;

static __device__ __forceinline__ short bf16bits(float x) {
    __hip_bfloat16 h = __float2bfloat16(x);
    return *reinterpret_cast<short*>(&h);
}
static __device__ __forceinline__ float bf16tof(short s) {
    unsigned int u = ((unsigned int)(unsigned short)s) << 16;
    return *reinterpret_cast<float*>(&u);
}

// ---------------- Kernel C: fused QKV projections via MFMA ---------------------
// Flat grid 768, XCD-paired swizzle. W-half staged into LDS fragments in two
// 4-tile phases (32 KB live); B-reads become conflict-free ds_read_b128.
// Epilogue: per-wave 16x16 D-tile via 512B LDS -> coalesced 8B/lane stores.
__global__ __launch_bounds__(256) void proj_mfma(
    const float* __restrict__ q_in, const float* __restrict__ k_in, const float* __restrict__ v_in,
    const float* __restrict__ Wq, const float* __restrict__ Wk, const float* __restrict__ Wv,
    const float* __restrict__ bq, const float* __restrict__ bk, const float* __restrict__ bv,
    short* __restrict__ Qf, short* __restrict__ Kf,
    short* __restrict__ Vf, float* __restrict__ sfull)
{
    const int gid   = blockIdx.x;            // 0..767
    const int low3  = gid & 7;
    const int nhalf = (gid >> 3) & 1;
    const int p     = (gid >> 4) * 8 + low3; // 0..383
    const int which = p >> 7;                // 0..2
    const int mblk  = p & 127;               // 0..127

    const float* X  = (which == 0) ? q_in : (which == 1) ? k_in : v_in;
    const float* W  = (which == 0) ? Wq : (which == 1) ? Wk : Wv;
    const float* bias = (which == 0) ? bq : (which == 1) ? bk : bv;

    if (which == 2) {
        int zb = mblk * 2 + nhalf;   // 0..255
        sfull[(size_t)zb * 256 + threadIdx.x] = 0.f;
    }

    const int tid  = threadIdx.x;
    const int wave = tid >> 6, lane = tid & 63;
    const int l15 = lane & 15, lhi = lane >> 4;
    const int m0 = mblk * 64 + wave * 16;
    const int n0 = nhalf * 128;

    __shared__ short Wl[4 * 32 * 16 * 8];   // 4 n-tiles x 32 k-chunks (32 KB)
    __shared__ short Dt[4][16][16];         // per-wave D-tile (512B each)

    const float* xrow = X + (size_t)(m0 + l15) * E + lhi * 8;

    f32x4 acc[8] = {};
    #pragma unroll
    for (int ph = 0; ph < 2; ++ph) {
        // ---- stage W cols [n0+ph*64, +64), all k, into LDS fragments ----
        __syncthreads();   // waves done reading previous phase's Wl
        #pragma unroll
        for (int it = 0; it < 16; ++it) {
            int k   = it * 16 + (tid >> 4);
            int nlq = (tid & 15) * 4;
            float4 w4 = *(const float4*)(W + (size_t)k * E + n0 + ph * 64 + nlq);
            #pragma unroll
            for (int e = 0; e < 4; ++e) {
                int nl = nlq + e;            // 0..63 within phase
                int idx = (((nl >> 4) * 32 + (k >> 3)) * 16 + (nl & 15)) * 8 + (k & 7);
                Wl[idx] = bf16bits(e == 0 ? w4.x : e == 1 ? w4.y : e == 2 ? w4.z : w4.w);
            }
        }
        __syncthreads();

        // ---- MFMA over this phase's 4 n-tiles ----
        for (int k0 = 0; k0 < E; k0 += 32) {
            float4 a0 = *(const float4*)(xrow + k0);
            float4 a1 = *(const float4*)(xrow + k0 + 4);
            short at[8];
            at[0] = bf16bits(a0.x); at[1] = bf16bits(a0.y);
            at[2] = bf16bits(a0.z); at[3] = bf16bits(a0.w);
            at[4] = bf16bits(a1.x); at[5] = bf16bits(a1.y);
            at[6] = bf16bits(a1.z); at[7] = bf16bits(a1.w);
            short8 af = *(short8*)at;
            #pragma unroll
            for (int ntl = 0; ntl < 4; ++ntl) {
                int bidx = ((ntl * 32 + (k0 >> 3) + lhi) * 16 + l15) * 8;
                short8 bf = *(const short8*)(Wl + bidx);
                acc[ph * 4 + ntl] = __builtin_amdgcn_mfma_f32_16x16x32_bf16(af, bf, acc[ph * 4 + ntl], 0, 0, 0);
            }
        }
    }

    // Epilogue: D row m = m0 + lhi*4 + j, col n = n0 + nt*16 + l15.
    short* dst;
    const int L = lane;
    #pragma unroll
    for (int nt = 0; nt < 8; ++nt) {
        const int ncol = n0 + nt * 16;
        #pragma unroll
        for (int j = 0; j < 4; ++j) {
            float v = acc[nt][j] + bias[ncol + l15];
            short sv = (which == 0) ? bf16bits(v * QSCALE) : bf16bits(v);
            Dt[wave][lhi * 4 + j][l15] = sv;
        }
        short4v rv = *(const short4v*)&Dt[wave][(L >> 1) & 15][(L >> 5) * 8 + (L & 1) * 4];

        size_t off;
        if (which == 2) {
            int tile = m0 >> 4;
            int kc0  = ncol >> 3;
            off = ((size_t)tile * 32 + kc0) * 128;
            dst = Vf;
        } else {
            int b = m0 >> 10, nl0 = m0 & (N - 1);
            int h = ncol >> 5;
            int tile = (b * H + h) * 64 + (nl0 >> 4);
            off = ((size_t)tile * 4 + ((ncol & 31) >> 3)) * 128;
            dst = (which == 0) ? Qf : Kf;
        }
        *(short4v*)(dst + off + (size_t)L * 4) = rv;
    }
}

// ---------------- Kernel D: fused scores softmax (single QK^T pass) ------------
// Grid (BH, 64 mc) x 512 threads (8 waves). Block: 16 m columns, ALL 1024 n.
// Exact r14 structure (best measured config).
__global__ __launch_bounds__(512, 4) void scores_fused(
    const short* __restrict__ Qf, const short* __restrict__ Kf,
    float* __restrict__ sfull)
{
    const int bh = blockIdx.x;   // 0..63
    const int mc = blockIdx.y;   // 0..63
    const int tid  = threadIdx.x;
    const int wave = tid >> 6;   // 0..7
    const int lane = tid & 63;
    const int l15  = lane & 15;
    const int lhi  = lane >> 4;

    const short* Qb = Qf + (size_t)bh * 32768;   // 64 tiles x 512 elems
    const short* Kb = Kf + (size_t)bh * 32768;

    __shared__ float zred[8][16];
    __shared__ float cinvS[16];

    short8 qf = *(const short8*)(Qb + ((size_t)mc * 4 + lhi) * 128 + l15 * 8);

    float z[4] = {0.f, 0.f, 0.f, 0.f};
    short4v ep[8];   // parked P = exp2(S), packed bf16 (16 VGPRs)

    // ---- Pass A ----
    #pragma unroll
    for (int ntl = 0; ntl < 8; ++ntl) {
        int nt = wave * 8 + ntl;
        short8 kf = *(const short8*)(Kb + ((size_t)nt * 4 + lhi) * 128 + l15 * 8);
        f32x4 acc = {0.f, 0.f, 0.f, 0.f};
        acc = __builtin_amdgcn_mfma_f32_16x16x32_bf16(qf, kf, acc, 0, 0, 0);
        float e0 = exp2f(acc[0]), e1 = exp2f(acc[1]);
        float e2 = exp2f(acc[2]), e3 = exp2f(acc[3]);
        z[0] += e0; z[1] += e1; z[2] += e2; z[3] += e3;
        short4v pk = { bf16bits(e0), bf16bits(e1), bf16bits(e2), bf16bits(e3) };
        ep[ntl] = pk;
    }

    // butterfly over l15 (sums the 16 n's per tile)
    #pragma unroll
    for (int j = 0; j < 4; ++j) {
        float v = z[j];
        v += __shfl_xor(v, 1); v += __shfl_xor(v, 2);
        v += __shfl_xor(v, 4); v += __shfl_xor(v, 8);
        z[j] = v;
    }
    if (l15 == 0) {
        #pragma unroll
        for (int j = 0; j < 4; ++j)
            zred[wave][lhi * 4 + j] = z[j];
    }
    __syncthreads();
    if (tid < 16) {
        float zs = 0.f;
        #pragma unroll
        for (int w = 0; w < 8; ++w) zs += zred[w][tid];
        cinvS[tid] = 1.0f / zs;
    }
    __syncthreads();

    float ci[4];
    #pragma unroll
    for (int j = 0; j < 4; ++j) ci[j] = cinvS[lhi * 4 + j];

    // ---- Pass B: pure-register weighted row sums -> fp32 atomics ----
    float* sf = sfull + (size_t)bh * N;
    #pragma unroll
    for (int ntl = 0; ntl < 8; ++ntl) {
        int nt = wave * 8 + ntl;
        float rp = bf16tof(ep[ntl][0]) * ci[0] + bf16tof(ep[ntl][1]) * ci[1]
                 + bf16tof(ep[ntl][2]) * ci[2] + bf16tof(ep[ntl][3]) * ci[3];
        rp += __shfl_xor(rp, 16);
        rp += __shfl_xor(rp, 32);
        if (lane < 16) atomicAdd(&sf[nt * 16 + l15], rp);
    }
}

// ---------------- Kernel F: output GEMM, V-scale fused in-register --------------
// Flat grid 512, XCD-paired swizzle: id = (q>>3)*32 + nb*8 + (q&7).
// Wo 64-col half staged into LDS fragments (32 KB) at block start.
__global__ __launch_bounds__(256) void out_mfma(
    const short* __restrict__ Vf, const float* __restrict__ sfull,
    const float* __restrict__ Wo,
    const float* __restrict__ bo, float* __restrict__ out)
{
    const int gid  = blockIdx.x;             // 0..511
    const int low3 = gid & 7;
    const int nb   = (gid >> 3) & 3;
    const int q    = (gid >> 5) * 8 + low3;  // 0..127

    const int tid  = threadIdx.x;
    const int wave = tid >> 6, lane = tid & 63;
    const int l15 = lane & 15, lhi = lane >> 4;
    const int m0 = q * 64 + wave * 16;
    const int n0 = nb * 64;

    __shared__ short Wl[4 * 32 * 16 * 8];   // 4 n-tiles x 32 k-chunks (32 KB)

    // ---- stage Wo cols [n0, n0+64), all k ----
    #pragma unroll
    for (int it = 0; it < 16; ++it) {
        int k   = it * 16 + (tid >> 4);
        int nlq = (tid & 15) * 4;
        float4 w4 = *(const float4*)(Wo + (size_t)k * E + n0 + nlq);
        #pragma unroll
        for (int e = 0; e < 4; ++e) {
            int nl = nlq + e;
            int idx = (((nl >> 4) * 32 + (k >> 3)) * 16 + (nl & 15)) * 8 + (k & 7);
            Wl[idx] = bf16bits(e == 0 ? w4.x : e == 1 ? w4.y : e == 2 ? w4.z : w4.w);
        }
    }

    // per-lane A-row scale, one per head (sfull is 256 KB -> L2-resident)
    const int r = m0 + l15;
    const int b = r >> 10, nl = r & (N - 1);
    float sarr[8];
    #pragma unroll
    for (int h = 0; h < 8; ++h)
        sarr[h] = sfull[(size_t)(b * H + h) * N + nl];

    __syncthreads();

    const short* vt = Vf + (size_t)(m0 >> 4) * 4096;   // V tile: 32 chunks x 128

    f32x4 acc[4] = {};
    for (int k0 = 0; k0 < E; k0 += 32) {
        const float s = sarr[k0 >> 5];
        short8 vv = *(const short8*)(vt + ((size_t)(k0 >> 3) + lhi) * 128 + l15 * 8);
        short at[8];
        #pragma unroll
        for (int i = 0; i < 8; ++i) at[i] = bf16bits(bf16tof(vv[i]) * s);
        short8 af = *(short8*)at;
        #pragma unroll
        for (int ntl = 0; ntl < 4; ++ntl) {
            int bidx = ((ntl * 32 + (k0 >> 3) + lhi) * 16 + l15) * 8;
            short8 bf = *(const short8*)(Wl + bidx);
            acc[ntl] = __builtin_amdgcn_mfma_f32_16x16x32_bf16(af, bf, acc[ntl], 0, 0, 0);
        }
    }
    #pragma unroll
    for (int nt = 0; nt < 4; ++nt) {
        #pragma unroll
        for (int j = 0; j < 4; ++j) {
            int m = m0 + lhi * 4 + j;
            int n = n0 + nt * 16 + l15;
            out[(size_t)m * E + n] = acc[nt][j] + bo[n];
        }
    }
}

// --------------------------------------------------------------------------------
extern "C" void kernel_launch(void* const* d_in, const int* in_sizes, int n_in,
                              void* d_out, int out_size, void* d_ws, size_t ws_size,
                              hipStream_t stream) {
    const float* q_in = (const float*)d_in[0];
    const float* k_in = (const float*)d_in[1];
    const float* v_in = (const float*)d_in[2];
    const float* Wq = (const float*)d_in[3];
    const float* bq = (const float*)d_in[4];
    const float* Wk = (const float*)d_in[5];
    const float* bk = (const float*)d_in[6];
    const float* Wv = (const float*)d_in[7];
    const float* bv = (const float*)d_in[8];
    const float* Wo = (const float*)d_in[9];
    const float* bo = (const float*)d_in[10];
    float* out = (float*)d_out;

    // Workspace layout (bytes):
    //   Qf    bf16 frag [BH*64][4][16][8]   @ 0      (4 MB)
    //   Kf    bf16 frag [BH*64][4][16][8]   @ 4 MB   (4 MB)
    //   Vf    bf16 frag [512][32][16][8]    @ 8 MB   (4 MB)
    //   sfull fp32 [BH][N]                  @ 12 MB  (256 KB)
    char* ws = (char*)d_ws;
    short* Qf    = (short*)ws;
    short* Kf    = (short*)(ws + (4u << 20));
    short* Vf    = (short*)(ws + (8u << 20));
    float* sfull = (float*)(ws + (12u << 20));

    proj_mfma<<<768, 256, 0, stream>>>(
        q_in, k_in, v_in, Wq, Wk, Wv, bq, bk, bv, Qf, Kf, Vf, sfull);

    scores_fused<<<dim3(BH, 64), 512, 0, stream>>>(Qf, Kf, sfull);

    out_mfma<<<512, 256, 0, stream>>>(Vf, sfull, Wo, bo, out);
}

// Round 20
// 59.868 us; speedup vs baseline: 1.4281x; 1.4281x over previous
//
#include <hip/hip_runtime.h>
#include <hip/hip_bf16.h>
#include <cstdint>
#include <cstddef>

// Problem constants (B=8, T=64, F=16, E=256, H=8)
constexpr int E = 256;
constexpr int H = 8;
constexpr int D = 32;        // head dim
constexpr int N = 1024;      // T*F positions per (b,h)
constexpr int R = 8192;      // B*N rows
constexpr int BH = 64;       // B*H
constexpr float SCALE = 0.17677669529663687f;   // 1/sqrt(32)
constexpr float LOG2E = 1.4426950408889634f;
constexpr float QSCALE = SCALE * LOG2E;          // folded into bf16 Q

// ---- MFMA fragment layout -------------------------------------------------
// idx = ((tile*CCH + (k>>3))*16 + (row&15))*8 + (k&7)
//   Q/K  : tile = bh*64 + (n>>4), CCH = 4  (D=32)
//   V    : tile = m>>4,           CCH = 32 (E=256)
//   W^T  : tile = w*16 + (n>>4),  CCH = 32 (k over E=256)

typedef __attribute__((ext_vector_type(8))) short short8;
typedef __attribute__((ext_vector_type(4))) short short4v;
typedef __attribute__((ext_vector_type(4))) float f32x4;

static __device__ __forceinline__ short bf16bits(float x) {
    __hip_bfloat16 h = __float2bfloat16(x);
    return *reinterpret_cast<short*>(&h);
}
static __device__ __forceinline__ float bf16tof(short s) {
    unsigned int u = ((unsigned int)(unsigned short)s) << 16;
    return *reinterpret_cast<float*>(&u);
}

// ---------------- Kernel B: transpose weights fp32 -> bf16 frag layout ---------
// 256 blocks (vs 64 in r18): each handles a 16(k) x 64(n) slice -> whole GPU
// participates; 1 float4 load + 4 LDS-transposed writes per thread.
__global__ __launch_bounds__(256) void convw_kernel(
    const float* __restrict__ Wq, const float* __restrict__ Wk,
    const float* __restrict__ Wv, const float* __restrict__ Wo,
    short* __restrict__ Wt4f)
{
    const int w = blockIdx.y;
    const float* src = (w == 0) ? Wq : (w == 1) ? Wk : (w == 2) ? Wv : Wo;
    const int bx   = blockIdx.x;      // 0..63
    const int tc   = bx & 3;          // 64-col tile
    const int tr16 = bx >> 2;         // 16-row k-slice
    __shared__ float tile[16][65];
    const int tid = threadIdx.x;

    {
        int r  = tid >> 4;            // 0..15
        int c4 = (tid & 15) * 4;      // 0..60
        float4 v = *(const float4*)(src + (size_t)(tr16 * 16 + r) * E + tc * 64 + c4);
        tile[r][c4] = v.x; tile[r][c4 + 1] = v.y;
        tile[r][c4 + 2] = v.z; tile[r][c4 + 3] = v.w;
    }
    __syncthreads();
    #pragma unroll
    for (int e = 0; e < 4; ++e) {
        int idx = tid + e * 256;
        int kk = idx & 15, nn = idx >> 4;    // kk 0..15, nn 0..63
        int k = tr16 * 16 + kk, n = tc * 64 + nn;
        size_t didx = ((((size_t)w * 16 + (n >> 4)) * 32 + (k >> 3)) * 16 + (n & 15)) * 8 + (k & 7);
        Wt4f[didx] = bf16bits(tile[kk][nn]);
    }
}

// ---------------- Kernel C: fused QKV projections via MFMA ---------------------
// Flat grid 768, XCD-paired swizzle. Epilogue routes each wave's 16x16 D-tile
// through a private 512B LDS tile so fragment stores become one coalesced
// 512B store per (wave, nt) instead of 64 scattered 2B stores.
__global__ __launch_bounds__(256) void proj_mfma(
    const float* __restrict__ q_in, const float* __restrict__ k_in, const float* __restrict__ v_in,
    const short* __restrict__ Wt4f,
    const float* __restrict__ bq, const float* __restrict__ bk, const float* __restrict__ bv,
    short* __restrict__ Qf, short* __restrict__ Kf,
    short* __restrict__ Vf, float* __restrict__ sfull)
{
    const int gid   = blockIdx.x;            // 0..767
    const int low3  = gid & 7;
    const int nhalf = (gid >> 3) & 1;
    const int p     = (gid >> 4) * 8 + low3; // 0..383
    const int which = p >> 7;                // 0..2
    const int mblk  = p & 127;               // 0..127

    const float* X  = (which == 0) ? q_in : (which == 1) ? k_in : v_in;
    const float* bias = (which == 0) ? bq : (which == 1) ? bk : bv;

    if (which == 2) {
        int zb = mblk * 2 + nhalf;   // 0..255
        sfull[(size_t)zb * 256 + threadIdx.x] = 0.f;
    }

    const int wave = threadIdx.x >> 6, lane = threadIdx.x & 63;
    const int l15 = lane & 15, lhi = lane >> 4;
    const int m0 = mblk * 64 + wave * 16;
    const int n0 = nhalf * 128;

    __shared__ short Dt[4][16][16];   // per-wave 16x16 bf16 D-tile (512B each)

    const float* xrow = X + (size_t)(m0 + l15) * E + lhi * 8;

    f32x4 acc[8] = {};
    for (int k0 = 0; k0 < E; k0 += 32) {
        float4 a0 = *(const float4*)(xrow + k0);
        float4 a1 = *(const float4*)(xrow + k0 + 4);
        short at[8];
        at[0] = bf16bits(a0.x); at[1] = bf16bits(a0.y);
        at[2] = bf16bits(a0.z); at[3] = bf16bits(a0.w);
        at[4] = bf16bits(a1.x); at[5] = bf16bits(a1.y);
        at[6] = bf16bits(a1.z); at[7] = bf16bits(a1.w);
        short8 af = *(short8*)at;
        #pragma unroll
        for (int nt = 0; nt < 8; ++nt) {
            size_t bidx = ((((size_t)which * 16 + (n0 >> 4) + nt) * 32 + (k0 >> 3) + lhi) * 16 + l15) * 8;
            short8 bf = *(const short8*)(Wt4f + bidx);
            acc[nt] = __builtin_amdgcn_mfma_f32_16x16x32_bf16(af, bf, acc[nt], 0, 0, 0);
        }
    }

    // Epilogue: D row m = m0 + lhi*4 + j, col n = n0 + nt*16 + l15.
    short* dst;
    const int L = lane;
    #pragma unroll
    for (int nt = 0; nt < 8; ++nt) {
        const int ncol = n0 + nt * 16;
        #pragma unroll
        for (int j = 0; j < 4; ++j) {
            float v = acc[nt][j] + bias[ncol + l15];
            short sv = (which == 0) ? bf16bits(v * QSCALE) : bf16bits(v);
            Dt[wave][lhi * 4 + j][l15] = sv;
        }
        short4v rv = *(const short4v*)&Dt[wave][(L >> 1) & 15][(L >> 5) * 8 + (L & 1) * 4];

        size_t off;
        if (which == 2) {
            int tile = m0 >> 4;
            int kc0  = ncol >> 3;
            off = ((size_t)tile * 32 + kc0) * 128;
            dst = Vf;
        } else {
            int b = m0 >> 10, nl0 = m0 & (N - 1);
            int h = ncol >> 5, dd0 = ncol & 31;
            int tile = (b * H + h) * 64 + (nl0 >> 4);
            off = ((size_t)tile * 4 + (dd0 >> 3)) * 128;
            dst = (which == 0) ? Qf : Kf;
        }
        *(short4v*)(dst + off + (size_t)L * 4) = rv;
    }
}

// ---------------- Kernel D: fused scores softmax (single QK^T pass) ------------
// Grid (BH, 64 mc) x 512 threads (8 waves). Block: 16 m columns, ALL 1024 n.
// Exact r14 structure (best measured: 60.7 us total).
__global__ __launch_bounds__(512, 4) void scores_fused(
    const short* __restrict__ Qf, const short* __restrict__ Kf,
    float* __restrict__ sfull)
{
    const int bh = blockIdx.x;   // 0..63
    const int mc = blockIdx.y;   // 0..63
    const int tid  = threadIdx.x;
    const int wave = tid >> 6;   // 0..7
    const int lane = tid & 63;
    const int l15  = lane & 15;
    const int lhi  = lane >> 4;

    const short* Qb = Qf + (size_t)bh * 32768;   // 64 tiles x 512 elems
    const short* Kb = Kf + (size_t)bh * 32768;

    __shared__ float zred[8][16];
    __shared__ float cinvS[16];

    short8 qf = *(const short8*)(Qb + ((size_t)mc * 4 + lhi) * 128 + l15 * 8);

    float z[4] = {0.f, 0.f, 0.f, 0.f};
    short4v ep[8];   // parked P = exp2(S), packed bf16 (16 VGPRs)

    // ---- Pass A ----
    #pragma unroll
    for (int ntl = 0; ntl < 8; ++ntl) {
        int nt = wave * 8 + ntl;
        short8 kf = *(const short8*)(Kb + ((size_t)nt * 4 + lhi) * 128 + l15 * 8);
        f32x4 acc = {0.f, 0.f, 0.f, 0.f};
        acc = __builtin_amdgcn_mfma_f32_16x16x32_bf16(qf, kf, acc, 0, 0, 0);
        float e0 = exp2f(acc[0]), e1 = exp2f(acc[1]);
        float e2 = exp2f(acc[2]), e3 = exp2f(acc[3]);
        z[0] += e0; z[1] += e1; z[2] += e2; z[3] += e3;
        short4v pk = { bf16bits(e0), bf16bits(e1), bf16bits(e2), bf16bits(e3) };
        ep[ntl] = pk;
    }

    // butterfly over l15 (sums the 16 n's per tile)
    #pragma unroll
    for (int j = 0; j < 4; ++j) {
        float v = z[j];
        v += __shfl_xor(v, 1); v += __shfl_xor(v, 2);
        v += __shfl_xor(v, 4); v += __shfl_xor(v, 8);
        z[j] = v;
    }
    if (l15 == 0) {
        #pragma unroll
        for (int j = 0; j < 4; ++j)
            zred[wave][lhi * 4 + j] = z[j];
    }
    __syncthreads();
    if (tid < 16) {
        float zs = 0.f;
        #pragma unroll
        for (int w = 0; w < 8; ++w) zs += zred[w][tid];
        cinvS[tid] = 1.0f / zs;
    }
    __syncthreads();

    float ci[4];
    #pragma unroll
    for (int j = 0; j < 4; ++j) ci[j] = cinvS[lhi * 4 + j];

    // ---- Pass B: pure-register weighted row sums -> fp32 atomics ----
    float* sf = sfull + (size_t)bh * N;
    #pragma unroll
    for (int ntl = 0; ntl < 8; ++ntl) {
        int nt = wave * 8 + ntl;
        float rp = bf16tof(ep[ntl][0]) * ci[0] + bf16tof(ep[ntl][1]) * ci[1]
                 + bf16tof(ep[ntl][2]) * ci[2] + bf16tof(ep[ntl][3]) * ci[3];
        rp += __shfl_xor(rp, 16);
        rp += __shfl_xor(rp, 32);
        if (lane < 16) atomicAdd(&sf[nt * 16 + l15], rp);
    }
}

// ---------------- Kernel F: output GEMM, V-scale fused in-register --------------
// Flat grid 512, XCD-paired swizzle: id = (q>>3)*32 + nb*8 + (q&7).
__global__ __launch_bounds__(256) void out_mfma(
    const short* __restrict__ Vf, const float* __restrict__ sfull,
    const short* __restrict__ Wt4f,
    const float* __restrict__ bo, float* __restrict__ out)
{
    const int gid  = blockIdx.x;             // 0..511
    const int low3 = gid & 7;
    const int nb   = (gid >> 3) & 3;
    const int q    = (gid >> 5) * 8 + low3;  // 0..127

    const int wave = threadIdx.x >> 6, lane = threadIdx.x & 63;
    const int l15 = lane & 15, lhi = lane >> 4;
    const int m0 = q * 64 + wave * 16;
    const int n0 = nb * 64;

    // per-lane A-row scale, one per head (sfull is 256 KB -> L2-resident)
    const int r = m0 + l15;
    const int b = r >> 10, nl = r & (N - 1);
    float sarr[8];
    #pragma unroll
    for (int h = 0; h < 8; ++h)
        sarr[h] = sfull[(size_t)(b * H + h) * N + nl];

    const short* vt = Vf + (size_t)(m0 >> 4) * 4096;   // V tile: 32 chunks x 128

    f32x4 acc[4] = {};
    for (int k0 = 0; k0 < E; k0 += 32) {
        const float s = sarr[k0 >> 5];
        short8 vv = *(const short8*)(vt + ((size_t)(k0 >> 3) + lhi) * 128 + l15 * 8);
        short at[8];
        #pragma unroll
        for (int i = 0; i < 8; ++i) at[i] = bf16bits(bf16tof(vv[i]) * s);
        short8 af = *(short8*)at;
        #pragma unroll
        for (int nt = 0; nt < 4; ++nt) {
            size_t bidx = ((((size_t)3 * 16 + (n0 >> 4) + nt) * 32 + (k0 >> 3) + lhi) * 16 + l15) * 8;
            short8 bf = *(const short8*)(Wt4f + bidx);
            acc[nt] = __builtin_amdgcn_mfma_f32_16x16x32_bf16(af, bf, acc[nt], 0, 0, 0);
        }
    }
    #pragma unroll
    for (int nt = 0; nt < 4; ++nt) {
        #pragma unroll
        for (int j = 0; j < 4; ++j) {
            int m = m0 + lhi * 4 + j;
            int n = n0 + nt * 16 + l15;
            out[(size_t)m * E + n] = acc[nt][j] + bo[n];
        }
    }
}

// --------------------------------------------------------------------------------
extern "C" void kernel_launch(void* const* d_in, const int* in_sizes, int n_in,
                              void* d_out, int out_size, void* d_ws, size_t ws_size,
                              hipStream_t stream) {
    const float* q_in = (const float*)d_in[0];
    const float* k_in = (const float*)d_in[1];
    const float* v_in = (const float*)d_in[2];
    const float* Wq = (const float*)d_in[3];
    const float* bq = (const float*)d_in[4];
    const float* Wk = (const float*)d_in[5];
    const float* bk = (const float*)d_in[6];
    const float* Wv = (const float*)d_in[7];
    const float* bv = (const float*)d_in[8];
    const float* Wo = (const float*)d_in[9];
    const float* bo = (const float*)d_in[10];
    float* out = (float*)d_out;

    // Workspace layout (bytes):
    //   Wt4f  bf16 frag [4][16][32][16][8]  @ 0        (512 KB)
    //   Qf    bf16 frag [BH*64][4][16][8]   @ 0.5 MB   (4 MB)
    //   Kf    bf16 frag [BH*64][4][16][8]   @ 4.5 MB   (4 MB)
    //   Vf    bf16 frag [512][32][16][8]    @ 8.5 MB   (4 MB)
    //   sfull fp32 [BH][N]                  @ 12.5 MB  (256 KB)
    char* ws = (char*)d_ws;
    short* Wt4f  = (short*)ws;
    short* Qf    = (short*)(ws + (512u << 10));
    short* Kf    = (short*)(ws + (4u << 20) + (512u << 10));
    short* Vf    = (short*)(ws + (8u << 20) + (512u << 10));
    float* sfull = (float*)(ws + (12u << 20) + (512u << 10));

    convw_kernel<<<dim3(64, 4), 256, 0, stream>>>(Wq, Wk, Wv, Wo, Wt4f);

    proj_mfma<<<768, 256, 0, stream>>>(
        q_in, k_in, v_in, Wt4f, bq, bk, bv, Qf, Kf, Vf, sfull);

    scores_fused<<<dim3(BH, 64), 512, 0, stream>>>(Qf, Kf, sfull);

    out_mfma<<<512, 256, 0, stream>>>(Vf, sfull, Wt4f, bo, out);
}